// Round 1
// 602.741 us; speedup vs baseline: 1.1041x; 1.1041x over previous
//
#include <hip/hip_runtime.h>

// Sparse average pooling: out[ro[r], c] += in[ri[r], c] / 8, C=64 fp32.
//
// Round-3 structure: bucket row = one 64B cache line = [count, e0..e14].
//  - count embedded in the row: gather does ONE dependent line read before
//    feature loads (was cnt -> list -> features, 3-deep chain).
//  - CAP_ENT=15 per bucket (P(overflow) ~ 3e-6/row, lambda=4); overflow pairs
//    go to a tiny list merged by an atomic kernel afterwards (usually ~0-2).
//  - build: 4 rules/thread via int4 loads; atomic + entry store hit the same
//    64B line per bucket.
//  - gather: q0,q1 (first 8 ints of the row) loaded unconditionally (same
//    line, 16-lane broadcast); q2/q3 gated on k>7 / k>11 (rare).
//  - output stored nontemporally (never re-read; keep L2 for input rows).

#define C_CHANNELS 64
#define ROW_INTS 16       // 64 B bucket row
#define CAP_ENT 15        // entries per bucket row (slot 0 is the count)
#define OVF_CAP 16384

typedef float f32x4 __attribute__((ext_vector_type(4)));

__global__ __launch_bounds__(256) void
zero_ws_kernel(int4* __restrict__ p, int n4, int* __restrict__ ovf_cnt) {
    int i = blockIdx.x * blockDim.x + threadIdx.x;
    int stride = gridDim.x * blockDim.x;
    int4 z = make_int4(0, 0, 0, 0);
    for (; i < n4; i += stride) p[i] = z;
    if (blockIdx.x == 0 && threadIdx.x == 0) *ovf_cnt = 0;
}

__device__ __forceinline__ void
push_rule(int ri, int ro,
          int* __restrict__ bucket,
          int* __restrict__ ovf_cnt,
          int2* __restrict__ ovf_pairs) {
    int* row = bucket + (size_t)ro * ROW_INTS;
    int pos = atomicAdd(row, 1);
    if (pos < CAP_ENT) {
        row[1 + pos] = ri;
    } else {
        int oi = atomicAdd(ovf_cnt, 1);
        if (oi < OVF_CAP) ovf_pairs[oi] = make_int2(ri, ro);
    }
}

__global__ __launch_bounds__(256) void
build_kernel(const int* __restrict__ rules_in,
             const int* __restrict__ rules_out,
             int* __restrict__ bucket,
             int* __restrict__ ovf_cnt,
             int2* __restrict__ ovf_pairs,
             int n_rules) {
    int t = blockIdx.x * blockDim.x + threadIdx.x;
    int r0 = t << 2;
    if (r0 >= n_rules) return;
    if (r0 + 4 <= n_rules) {
        int4 ri4 = *reinterpret_cast<const int4*>(rules_in + r0);
        int4 ro4 = *reinterpret_cast<const int4*>(rules_out + r0);
        push_rule(ri4.x, ro4.x, bucket, ovf_cnt, ovf_pairs);
        push_rule(ri4.y, ro4.y, bucket, ovf_cnt, ovf_pairs);
        push_rule(ri4.z, ro4.z, bucket, ovf_cnt, ovf_pairs);
        push_rule(ri4.w, ro4.w, bucket, ovf_cnt, ovf_pairs);
    } else {
        for (int r = r0; r < n_rules; ++r)
            push_rule(rules_in[r], rules_out[r], bucket, ovf_cnt, ovf_pairs);
    }
}

__global__ __launch_bounds__(256) void
gather_kernel(const float* __restrict__ in,
              const int* __restrict__ bucket,
              float* __restrict__ out,
              int n_out) {
    int idx = blockIdx.x * blockDim.x + threadIdx.x;
    int ro = idx >> 4;            // 16 lanes per output row
    int c4 = (idx & 15) << 2;     // 4 channels per lane
    if (ro >= n_out) return;

    const int4* row = reinterpret_cast<const int4*>(bucket + (size_t)ro * ROW_INTS);
    // One 64B line; all 16 lanes of this group broadcast from it.
    int4 q0 = row[0];
    int4 q1 = row[1];
    int k = q0.x < CAP_ENT ? q0.x : CAP_ENT;

    f32x4 s = {0.f, 0.f, 0.f, 0.f};

#define ACC(ridx) \
    s += *reinterpret_cast<const f32x4*>(in + (size_t)(unsigned)(ridx) * C_CHANNELS + c4)

    if (k > 0) {
        ACC(q0.y);
        if (k > 1)  ACC(q0.z);
        if (k > 2)  ACC(q0.w);
        if (k > 3)  ACC(q1.x);
        if (k > 4)  ACC(q1.y);
        if (k > 5)  ACC(q1.z);
        if (k > 6)  ACC(q1.w);
        if (k > 7) {
            int4 q2 = row[2];
            ACC(q2.x);
            if (k > 8)  ACC(q2.y);
            if (k > 9)  ACC(q2.z);
            if (k > 10) ACC(q2.w);
            if (k > 11) {
                int4 q3 = row[3];
                ACC(q3.x);
                if (k > 12) ACC(q3.y);
                if (k > 13) ACC(q3.z);
                if (k > 14) ACC(q3.w);
            }
        }
    }
#undef ACC

    f32x4 o = s * 0.125f;
    __builtin_nontemporal_store(
        o, reinterpret_cast<f32x4*>(out + (size_t)ro * C_CHANNELS + c4));
}

__global__ __launch_bounds__(256) void
ovf_scatter_kernel(const float* __restrict__ in,
                   const int* __restrict__ ovf_cnt,
                   const int2* __restrict__ ovf_pairs,
                   float* __restrict__ out) {
    int n = *ovf_cnt;
    if (n > OVF_CAP) n = OVF_CAP;
    int total = n * 16;
    int stride = gridDim.x * blockDim.x;
    for (int idx = blockIdx.x * blockDim.x + threadIdx.x; idx < total; idx += stride) {
        int p  = idx >> 4;
        int c4 = (idx & 15) << 2;
        int2 pr = ovf_pairs[p];
        const float4 v = *reinterpret_cast<const float4*>(
            in + (size_t)pr.x * C_CHANNELS + c4);
        float* o = out + (size_t)pr.y * C_CHANNELS + c4;
        atomicAdd(o + 0, v.x * 0.125f);
        atomicAdd(o + 1, v.y * 0.125f);
        atomicAdd(o + 2, v.z * 0.125f);
        atomicAdd(o + 3, v.w * 0.125f);
    }
}

// ---- Fallback (ws too small): scatter-atomic path ----
__global__ __launch_bounds__(256) void
zero4_kernel(float4* __restrict__ p, long n4) {
    long i = (long)blockIdx.x * blockDim.x + threadIdx.x;
    long stride = (long)gridDim.x * blockDim.x;
    float4 z = {0.f, 0.f, 0.f, 0.f};
    for (; i < n4; i += stride) p[i] = z;
}

__global__ __launch_bounds__(256) void
avgpool_scatter_kernel(const float* __restrict__ in,
                       const int* __restrict__ rules_in,
                       const int* __restrict__ rules_out,
                       float* __restrict__ out,
                       int n_rules) {
    int idx = blockIdx.x * blockDim.x + threadIdx.x;
    int rule = idx >> 4;
    int c4   = (idx & 15) << 2;
    if (rule >= n_rules) return;
    int ri = rules_in[rule];
    int ro = rules_out[rule];
    const float4 v = *reinterpret_cast<const float4*>(
        in + (size_t)ri * C_CHANNELS + c4);
    float* o = out + (size_t)ro * C_CHANNELS + c4;
    atomicAdd(o + 0, v.x * 0.125f);
    atomicAdd(o + 1, v.y * 0.125f);
    atomicAdd(o + 2, v.z * 0.125f);
    atomicAdd(o + 3, v.w * 0.125f);
}

extern "C" void kernel_launch(void* const* d_in, const int* in_sizes, int n_in,
                              void* d_out, int out_size, void* d_ws, size_t ws_size,
                              hipStream_t stream) {
    const float* in        = (const float*)d_in[0];
    const int*   rules_in  = (const int*)d_in[1];
    const int*   rules_out = (const int*)d_in[2];
    float*       out       = (float*)d_out;

    const int n_rules = in_sizes[1];            // 1,500,000
    const int n_out   = out_size / C_CHANNELS;  // 375,000

    // Workspace layout (16B-aligned):
    //   [bucket: n_out * 16 ints (64B rows)][ovf_cnt: 16B][ovf_pairs: OVF_CAP int2]
    size_t list_bytes = (size_t)n_out * ROW_INTS * sizeof(int);   // 24 MB
    size_t list_pad   = (list_bytes + 15) & ~(size_t)15;
    size_t ovf_hdr    = 16;
    size_t need = list_pad + ovf_hdr + (size_t)OVF_CAP * sizeof(int2);

    const int block = 256;

    if (ws_size < need) {
        // Fallback: zero out, then scatter atomics.
        long n4 = (long)out_size / 4;
        int grid = (int)((n4 + block - 1) / block);
        if (grid > 65535) grid = 65535;
        zero4_kernel<<<grid, block, 0, stream>>>((float4*)out, n4);
        int total = n_rules * 16;
        avgpool_scatter_kernel<<<(total + block - 1) / block, block, 0, stream>>>(
            in, rules_in, rules_out, out, n_rules);
        return;
    }

    int*  bucket    = (int*)d_ws;
    int*  ovf_cnt   = (int*)((char*)d_ws + list_pad);
    int2* ovf_pairs = (int2*)((char*)d_ws + list_pad + ovf_hdr);

    // Pass 0: zero bucket rows (24 MB dense, ~4 us) + overflow counter.
    {
        int n4 = (int)(list_bytes / 16);   // n_out * 4 int4s
        int grid = (n4 + block - 1) / block;
        zero_ws_kernel<<<grid, block, 0, stream>>>((int4*)bucket, n4, ovf_cnt);
    }

    // Pass 1: build bucket rows (4 rules/thread, int4 rule loads).
    {
        int threads = (n_rules + 3) / 4;
        build_kernel<<<(threads + block - 1) / block, block, 0, stream>>>(
            rules_in, rules_out, bucket, ovf_cnt, ovf_pairs, n_rules);
    }

    // Pass 2: gather + single coalesced nontemporal store per row.
    {
        long total = (long)n_out * 16;
        int grid = (int)((total + block - 1) / block);
        gather_kernel<<<grid, block, 0, stream>>>(in, bucket, out, n_out);
    }

    // Pass 3: merge deferred overflow contributions (usually ~0-2 pairs).
    ovf_scatter_kernel<<<64, block, 0, stream>>>(in, ovf_cnt, ovf_pairs, out);
}

// Round 2
// 587.869 us; speedup vs baseline: 1.1320x; 1.0253x over previous
//
#include <hip/hip_runtime.h>

// Sparse average pooling: out[ro[r], c] += in[ri[r], c] / 8, C=64 fp32.
//
// Round-4: attack exposed memory latency (MLP=1 chains), not traffic.
//  - gather: workspace is zeroed, so unused entry slots hold 0 -> always a
//    valid row index. Load all 7 first-line entries UNCONDITIONALLY (dead
//    slots broadcast-read row 0: L1/L2-hot), predicate only the adds with
//    float masks. 9 loads in flight vs 1-2 in the old branchy cascade.
//    k>7 tail (5% of rows at lambda=4) stays branchy.
//  - build: 8 rules/thread; issue all 8 bucket atomics first, do the
//    dependent entry-stores after -> 8 RMWs in flight instead of 1.
//  - bucket row = one 64B line = [count, e0..e14]; overflow -> tiny pair
//    list merged by atomic kernel (expected ~0 pairs at CAP_ENT=15).

#define C_CHANNELS 64
#define ROW_INTS 16       // 64 B bucket row
#define CAP_ENT 15        // entries per bucket row (slot 0 is the count)
#define OVF_CAP 16384

typedef float f32x4 __attribute__((ext_vector_type(4)));

__global__ __launch_bounds__(256) void
zero_ws_kernel(int4* __restrict__ p, int n4, int* __restrict__ ovf_cnt) {
    int i = blockIdx.x * blockDim.x + threadIdx.x;
    int stride = gridDim.x * blockDim.x;
    int4 z = make_int4(0, 0, 0, 0);
    for (; i < n4; i += stride) p[i] = z;
    if (blockIdx.x == 0 && threadIdx.x == 0) *ovf_cnt = 0;
}

__device__ __forceinline__ void
store_entry(int* __restrict__ row, int pos, int ri,
            int ro, int* __restrict__ ovf_cnt, int2* __restrict__ ovf_pairs) {
    if (pos < CAP_ENT) {
        row[1 + pos] = ri;
    } else {
        int oi = atomicAdd(ovf_cnt, 1);
        if (oi < OVF_CAP) ovf_pairs[oi] = make_int2(ri, ro);
    }
}

__global__ __launch_bounds__(256) void
build_kernel(const int* __restrict__ rules_in,
             const int* __restrict__ rules_out,
             int* __restrict__ bucket,
             int* __restrict__ ovf_cnt,
             int2* __restrict__ ovf_pairs,
             int n_rules) {
    int t = blockIdx.x * blockDim.x + threadIdx.x;
    int r0 = t << 3;
    if (r0 >= n_rules) return;
    if (r0 + 8 <= n_rules) {
        int4 ia = *reinterpret_cast<const int4*>(rules_in + r0);
        int4 ib = *reinterpret_cast<const int4*>(rules_in + r0 + 4);
        int4 oa = *reinterpret_cast<const int4*>(rules_out + r0);
        int4 ob = *reinterpret_cast<const int4*>(rules_out + r0 + 4);
        int* p0 = bucket + (size_t)oa.x * ROW_INTS;
        int* p1 = bucket + (size_t)oa.y * ROW_INTS;
        int* p2 = bucket + (size_t)oa.z * ROW_INTS;
        int* p3 = bucket + (size_t)oa.w * ROW_INTS;
        int* p4 = bucket + (size_t)ob.x * ROW_INTS;
        int* p5 = bucket + (size_t)ob.y * ROW_INTS;
        int* p6 = bucket + (size_t)ob.z * ROW_INTS;
        int* p7 = bucket + (size_t)ob.w * ROW_INTS;
        // Issue all 8 RMWs before any dependent store.
        int s0 = atomicAdd(p0, 1);
        int s1 = atomicAdd(p1, 1);
        int s2 = atomicAdd(p2, 1);
        int s3 = atomicAdd(p3, 1);
        int s4 = atomicAdd(p4, 1);
        int s5 = atomicAdd(p5, 1);
        int s6 = atomicAdd(p6, 1);
        int s7 = atomicAdd(p7, 1);
        store_entry(p0, s0, ia.x, oa.x, ovf_cnt, ovf_pairs);
        store_entry(p1, s1, ia.y, oa.y, ovf_cnt, ovf_pairs);
        store_entry(p2, s2, ia.z, oa.z, ovf_cnt, ovf_pairs);
        store_entry(p3, s3, ia.w, oa.w, ovf_cnt, ovf_pairs);
        store_entry(p4, s4, ib.x, ob.x, ovf_cnt, ovf_pairs);
        store_entry(p5, s5, ib.y, ob.y, ovf_cnt, ovf_pairs);
        store_entry(p6, s6, ib.z, ob.z, ovf_cnt, ovf_pairs);
        store_entry(p7, s7, ib.w, ob.w, ovf_cnt, ovf_pairs);
    } else {
        for (int r = r0; r < n_rules; ++r) {
            int ro = rules_out[r];
            int* row = bucket + (size_t)ro * ROW_INTS;
            int pos = atomicAdd(row, 1);
            store_entry(row, pos, rules_in[r], ro, ovf_cnt, ovf_pairs);
        }
    }
}

__global__ __launch_bounds__(256) void
gather_kernel(const float* __restrict__ in,
              const int* __restrict__ bucket,
              float* __restrict__ out,
              int n_out) {
    int idx = blockIdx.x * blockDim.x + threadIdx.x;
    int ro = idx >> 4;            // 16 lanes per output row
    int c4 = (idx & 15) << 2;     // 4 channels per lane
    if (ro >= n_out) return;

    const int4* row = reinterpret_cast<const int4*>(bucket + (size_t)ro * ROW_INTS);
    int4 q0 = row[0];
    int4 q1 = row[1];
    int k = q0.x < CAP_ENT ? q0.x : CAP_ENT;

    const float* base = in + c4;
#define LDV(r) (*reinterpret_cast<const f32x4*>(base + (size_t)(unsigned)(r) * C_CHANNELS))

    // Unused slots are 0 (ws zeroed) -> always-valid indices. Load all 7
    // unconditionally (MLP), predicate the adds.
    f32x4 v0 = LDV(q0.y);
    f32x4 v1 = LDV(q0.z);
    f32x4 v2 = LDV(q0.w);
    f32x4 v3 = LDV(q1.x);
    f32x4 v4 = LDV(q1.y);
    f32x4 v5 = LDV(q1.z);
    f32x4 v6 = LDV(q1.w);

    float m0 = k > 0 ? 1.f : 0.f;
    float m1 = k > 1 ? 1.f : 0.f;
    float m2 = k > 2 ? 1.f : 0.f;
    float m3 = k > 3 ? 1.f : 0.f;
    float m4 = k > 4 ? 1.f : 0.f;
    float m5 = k > 5 ? 1.f : 0.f;
    float m6 = k > 6 ? 1.f : 0.f;

    f32x4 s = v0 * m0;
    s += v1 * m1;
    s += v2 * m2;
    s += v3 * m3;
    s += v4 * m4;
    s += v5 * m5;
    s += v6 * m6;

    if (k > 7) {               // ~5% of rows at lambda=4
        int4 q2 = row[2];
        int4 q3 = row[3];
        f32x4 w0 = LDV(q2.x);
        f32x4 w1 = LDV(q2.y);
        f32x4 w2 = LDV(q2.z);
        f32x4 w3 = LDV(q2.w);
        f32x4 w4 = LDV(q3.x);
        f32x4 w5 = LDV(q3.y);
        f32x4 w6 = LDV(q3.z);
        f32x4 w7 = LDV(q3.w);
        s += w0;   // k > 7 guaranteed here
        s += w1 * (k > 8  ? 1.f : 0.f);
        s += w2 * (k > 9  ? 1.f : 0.f);
        s += w3 * (k > 10 ? 1.f : 0.f);
        s += w4 * (k > 11 ? 1.f : 0.f);
        s += w5 * (k > 12 ? 1.f : 0.f);
        s += w6 * (k > 13 ? 1.f : 0.f);
        s += w7 * (k > 14 ? 1.f : 0.f);
    }
#undef LDV

    f32x4 o = s * 0.125f;
    __builtin_nontemporal_store(
        o, reinterpret_cast<f32x4*>(out + (size_t)ro * C_CHANNELS + c4));
}

__global__ __launch_bounds__(256) void
ovf_scatter_kernel(const float* __restrict__ in,
                   const int* __restrict__ ovf_cnt,
                   const int2* __restrict__ ovf_pairs,
                   float* __restrict__ out) {
    int n = *ovf_cnt;
    if (n > OVF_CAP) n = OVF_CAP;
    int total = n * 16;
    int stride = gridDim.x * blockDim.x;
    for (int idx = blockIdx.x * blockDim.x + threadIdx.x; idx < total; idx += stride) {
        int p  = idx >> 4;
        int c4 = (idx & 15) << 2;
        int2 pr = ovf_pairs[p];
        const float4 v = *reinterpret_cast<const float4*>(
            in + (size_t)pr.x * C_CHANNELS + c4);
        float* o = out + (size_t)pr.y * C_CHANNELS + c4;
        atomicAdd(o + 0, v.x * 0.125f);
        atomicAdd(o + 1, v.y * 0.125f);
        atomicAdd(o + 2, v.z * 0.125f);
        atomicAdd(o + 3, v.w * 0.125f);
    }
}

// ---- Fallback (ws too small): scatter-atomic path ----
__global__ __launch_bounds__(256) void
zero4_kernel(float4* __restrict__ p, long n4) {
    long i = (long)blockIdx.x * blockDim.x + threadIdx.x;
    long stride = (long)gridDim.x * blockDim.x;
    float4 z = {0.f, 0.f, 0.f, 0.f};
    for (; i < n4; i += stride) p[i] = z;
}

__global__ __launch_bounds__(256) void
avgpool_scatter_kernel(const float* __restrict__ in,
                       const int* __restrict__ rules_in,
                       const int* __restrict__ rules_out,
                       float* __restrict__ out,
                       int n_rules) {
    int idx = blockIdx.x * blockDim.x + threadIdx.x;
    int rule = idx >> 4;
    int c4   = (idx & 15) << 2;
    if (rule >= n_rules) return;
    int ri = rules_in[rule];
    int ro = rules_out[rule];
    const float4 v = *reinterpret_cast<const float4*>(
        in + (size_t)ri * C_CHANNELS + c4);
    float* o = out + (size_t)ro * C_CHANNELS + c4;
    atomicAdd(o + 0, v.x * 0.125f);
    atomicAdd(o + 1, v.y * 0.125f);
    atomicAdd(o + 2, v.z * 0.125f);
    atomicAdd(o + 3, v.w * 0.125f);
}

extern "C" void kernel_launch(void* const* d_in, const int* in_sizes, int n_in,
                              void* d_out, int out_size, void* d_ws, size_t ws_size,
                              hipStream_t stream) {
    const float* in        = (const float*)d_in[0];
    const int*   rules_in  = (const int*)d_in[1];
    const int*   rules_out = (const int*)d_in[2];
    float*       out       = (float*)d_out;

    const int n_rules = in_sizes[1];            // 1,500,000
    const int n_out   = out_size / C_CHANNELS;  // 375,000

    // Workspace layout (16B-aligned):
    //   [bucket: n_out * 16 ints (64B rows)][ovf_cnt: 16B][ovf_pairs: OVF_CAP int2]
    size_t list_bytes = (size_t)n_out * ROW_INTS * sizeof(int);   // 24 MB
    size_t list_pad   = (list_bytes + 15) & ~(size_t)15;
    size_t ovf_hdr    = 16;
    size_t need = list_pad + ovf_hdr + (size_t)OVF_CAP * sizeof(int2);

    const int block = 256;

    if (ws_size < need) {
        // Fallback: zero out, then scatter atomics.
        long n4 = (long)out_size / 4;
        int grid = (int)((n4 + block - 1) / block);
        if (grid > 65535) grid = 65535;
        zero4_kernel<<<grid, block, 0, stream>>>((float4*)out, n4);
        int total = n_rules * 16;
        avgpool_scatter_kernel<<<(total + block - 1) / block, block, 0, stream>>>(
            in, rules_in, rules_out, out, n_rules);
        return;
    }

    int*  bucket    = (int*)d_ws;
    int*  ovf_cnt   = (int*)((char*)d_ws + list_pad);
    int2* ovf_pairs = (int2*)((char*)d_ws + list_pad + ovf_hdr);

    // Pass 0: zero bucket rows (24 MB dense) + overflow counter.
    {
        int n4 = (int)(list_bytes / 16);   // n_out * 4 int4s
        int grid = (n4 + block - 1) / block;
        zero_ws_kernel<<<grid, block, 0, stream>>>((int4*)bucket, n4, ovf_cnt);
    }

    // Pass 1: build bucket rows (8 rules/thread, atomics batched before stores).
    {
        int threads = (n_rules + 7) / 8;
        build_kernel<<<(threads + block - 1) / block, block, 0, stream>>>(
            rules_in, rules_out, bucket, ovf_cnt, ovf_pairs, n_rules);
    }

    // Pass 2: gather, full-MLP predicated loads, nontemporal store.
    {
        long total = (long)n_out * 16;
        int grid = (int)((total + block - 1) / block);
        gather_kernel<<<grid, block, 0, stream>>>(in, bucket, out, n_out);
    }

    // Pass 3: merge deferred overflow contributions (usually 0 pairs).
    ovf_scatter_kernel<<<64, block, 0, stream>>>(in, ovf_cnt, ovf_pairs, out);
}